// Round 1
// 432.681 us; speedup vs baseline: 1.0000x; 1.0000x over previous
//
#include <hip/hip_runtime.h>

// SpanPooler: x [1, 64, 2048, 768] fp32, spans [64, 2] int32 -> out [64, 768] fp32
// out[b, :] = mean(x[0, b, a:e, :]) where (a, e) = spans[b], count >= 1.
//
// Single-dispatch version: no memset, no atomics. Columns are independent, so
// we split columns (not rows) across blocks: grid = (B, CSPLIT). Each block
// owns 48 float4-columns of one batch; 8 row-groups stride the span rows,
// reduce through LDS, and row-group 0 stores the final scaled mean directly.
// Every output float is written exactly once -> poisoned d_out is fully
// overwritten, no zeroing dispatch required.

#define B_SZ   64
#define S_SZ   2048
#define D_SZ   768
#define D4     (D_SZ / 4)      // 192 float4 per row
#define CSPLIT 4               // column splits -> grid (64, 4) = 256 blocks
#define C4     (D4 / CSPLIT)   // 48 float4-columns per block (768 B segments)
#define RG     8               // row-groups per block
#define TPB    (C4 * RG)       // 384 threads = 6 waves

__global__ __launch_bounds__(TPB) void span_mean(
    const float* __restrict__ x,
    const int* __restrict__ spans,
    float* __restrict__ out) {
    const int b  = blockIdx.x;
    const int cs = blockIdx.y;          // column-split index 0..CSPLIT-1
    const int t  = threadIdx.x;         // 0 .. 383
    const int c  = t % C4;              // local float4 column 0..47
    const int rg = t / C4;              // row-group 0..7

    const int a = spans[2 * b + 0];
    const int e = spans[2 * b + 1];
    int cnt = e - a;
    if (cnt < 1) cnt = 1;
    const float inv = 1.0f / (float)cnt;

    const int col4 = cs * C4 + c;       // global float4 column 0..191
    const float4* row_base = (const float4*)(x + (size_t)b * S_SZ * D_SZ);

    // Row-group rg covers rows a+rg, a+rg+RG, ... (each span row exactly once
    // across the 8 row-groups). <= 16 independent loads per thread.
    float4 acc = make_float4(0.f, 0.f, 0.f, 0.f);
    for (int r = a + rg; r < e; r += RG) {
        float4 v = row_base[(size_t)r * D4 + col4];
        acc.x += v.x; acc.y += v.y; acc.z += v.z; acc.w += v.w;
    }

    // Reduce the 8 row-groups through LDS (6 KiB), then direct final store.
    __shared__ float4 sm[RG][C4];
    sm[rg][c] = acc;
    __syncthreads();

    if (rg == 0) {
        float4 s = sm[0][c];
        #pragma unroll
        for (int g = 1; g < RG; ++g) {
            float4 v = sm[g][c];
            s.x += v.x; s.y += v.y; s.z += v.z; s.w += v.w;
        }
        float4 o;
        o.x = s.x * inv; o.y = s.y * inv; o.z = s.z * inv; o.w = s.w * inv;
        ((float4*)(out + (size_t)b * D_SZ))[col4] = o;
    }
}

extern "C" void kernel_launch(void* const* d_in, const int* in_sizes, int n_in,
                              void* d_out, int out_size, void* d_ws, size_t ws_size,
                              hipStream_t stream) {
    const float* x   = (const float*)d_in[0];
    const int* spans = (const int*)d_in[1];
    float* out       = (float*)d_out;

    // Single dispatch: kernel writes every output element (no memset needed
    // even though d_out is re-poisoned 0xAA before every timed launch).
    span_mean<<<dim3(B_SZ, CSPLIT), dim3(TPB), 0, stream>>>(x, spans, out);
}